// Round 5
// baseline (612.283 us; speedup 1.0000x reference)
//
#include <hip/hip_runtime.h>

#define N_NODES 50000
#define N_EDGES 800000
#define F_INDIM 512
#define HID     256
#define N_CLS   64
#define K_STEPS 10
#define ALPHA_V 0.1f

typedef __attribute__((ext_vector_type(8))) short short8;
typedef __attribute__((ext_vector_type(4))) float f32x4;
typedef __attribute__((ext_vector_type(4))) unsigned short ushort4v;

__device__ __forceinline__ unsigned short f2bf(float f) {
  unsigned u = __builtin_bit_cast(unsigned, f);
  unsigned r = (u + 0x7fffu + ((u >> 16) & 1u)) >> 16;
  return (unsigned short)r;
}
__device__ __forceinline__ float bflo(unsigned g) {  // low bf16 of packed uint
  return __builtin_bit_cast(float, g << 16);
}
__device__ __forceinline__ float bfhi(unsigned g) {  // high bf16
  return __builtin_bit_cast(float, g & 0xffff0000u);
}

#define GLOAD_LDS16(g, l)                                                        \
  __builtin_amdgcn_global_load_lds(                                              \
      (const __attribute__((address_space(1))) unsigned int*)(g),                \
      (__attribute__((address_space(3))) unsigned int*)(l), 16, 0, 0)

// ---------------- edge dtype detection ----------------
__global__ void detect_kernel(const int* __restrict__ eb, int* __restrict__ flag) {
  __shared__ int any;
  if (threadIdx.x == 0) any = 0;
  __syncthreads();
  for (int j = threadIdx.x; j < 1024; j += 256) {
    if (eb[2 * j + 1] != 0) atomicOr(&any, 1);
  }
  __syncthreads();
  if (threadIdx.x == 0) flag[0] = any ? 0 : 1;  // 1 => int64 stride, 0 => int32
}

// ---------------- degree histogram over targets ----------------
__global__ void count_kernel(const int* __restrict__ eb, const int* __restrict__ flagp,
                             int* __restrict__ cnt) {
  int e = blockIdx.x * 256 + threadIdx.x;
  if (e >= N_EDGES) return;
  int sh = flagp[0];
  int c = eb[((size_t)(N_EDGES + e)) << sh];
  atomicAdd(&cnt[c], 1);
}

// ---------------- 3-kernel exclusive scan ----------------
__global__ void scan1_kernel(const int* __restrict__ cnt, int* __restrict__ ptr,
                             int* __restrict__ bsum) {
  __shared__ int sm[256];
  int t = threadIdx.x;
  int i = blockIdx.x * 256 + t;
  int v = (i < N_NODES) ? cnt[i] : 0;
  sm[t] = v;
  __syncthreads();
  for (int off = 1; off < 256; off <<= 1) {
    int x = sm[t];
    if (t >= off) x += sm[t - off];
    __syncthreads();
    sm[t] = x;
    __syncthreads();
  }
  int incl = sm[t];
  if (i < N_NODES) ptr[i] = incl - v;
  if (t == 255) bsum[blockIdx.x] = incl;
}

__global__ void scan2_kernel(int* __restrict__ bsum, int nblk) {
  __shared__ int sm[256];
  int t = threadIdx.x;
  int v = (t < nblk) ? bsum[t] : 0;
  sm[t] = v;
  __syncthreads();
  for (int off = 1; off < 256; off <<= 1) {
    int x = sm[t];
    if (t >= off) x += sm[t - off];
    __syncthreads();
    sm[t] = x;
    __syncthreads();
  }
  int incl = sm[t];
  if (t < nblk) bsum[t] = incl - v;
}

__global__ void scan3_kernel(int* __restrict__ ptr, const int* __restrict__ bsum) {
  int i = blockIdx.x * 256 + threadIdx.x;
  if (i < N_NODES) ptr[i] += bsum[i >> 8];
  if (i == 0) ptr[N_NODES] = N_EDGES;
}

// ---------------- dinv + selfw + cursor init ----------------
__global__ void dinv_kernel(const int* __restrict__ cnt, const int* __restrict__ ptr,
                            float* __restrict__ dinv, float* __restrict__ selfw,
                            int* __restrict__ cursor) {
  int i = blockIdx.x * 256 + threadIdx.x;
  if (i >= N_NODES) return;
  float di = rsqrtf((float)cnt[i] + 1.0f);
  dinv[i] = di;
  selfw[i] = (1.0f - ALPHA_V) * di * di;
  cursor[i] = ptr[i];
}

// ---------------- CSR fill (by target), packed (src, weight) ----------------
__global__ void fill_kernel(const int* __restrict__ eb, const int* __restrict__ flagp,
                            const float* __restrict__ dinv, int* __restrict__ cursor,
                            int2* __restrict__ epack) {
  int e = blockIdx.x * 256 + threadIdx.x;
  if (e >= N_EDGES) return;
  int sh = flagp[0];
  int r = eb[((size_t)e) << sh];
  int c = eb[((size_t)(N_EDGES + e)) << sh];
  int pos = atomicAdd(&cursor[c], 1);
  float w = (1.0f - ALPHA_V) * dinv[r] * dinv[c];
  epack[pos] = make_int2(r, __float_as_int(w));
}

// ---------------- weight transpose + bf16 prepass ----------------
__global__ void prep_w(const float* __restrict__ W1, const float* __restrict__ W2,
                       unsigned short* __restrict__ W1T, unsigned short* __restrict__ W2T) {
  int i = blockIdx.x * 256 + threadIdx.x;
  if (i < F_INDIM * HID) {
    int k = i >> 8, c = i & 255;
    W1T[(size_t)c * F_INDIM + k] = f2bf(W1[i]);
  }
  int j = i - F_INDIM * HID;
  if (j >= 0 && j < HID * N_CLS) {
    int k = j >> 6, c = j & 63;
    W2T[(size_t)c * HID + k] = f2bf(W2[j]);
  }
}

// ---------------- GEMM1: h = relu(x @ W1 + b1), bf16 MFMA ----------------
__global__ __launch_bounds__(256, 4) void gemm1_mfma(
    const float* __restrict__ A, const unsigned short* __restrict__ BT,
    const float* __restrict__ bias, unsigned short* __restrict__ H, int M) {
  __shared__ unsigned short Ab[2][64 * 32];    // 4 KB each
  __shared__ unsigned short Bb[2][128 * 32];   // 8 KB each
  const int t = threadIdx.x;
  const int wave = t >> 6, lane = t & 63;
  const int l15 = lane & 15, l4 = lane >> 4;
  const int row0 = blockIdx.x * 64, col0 = blockIdx.y * 128;

  f32x4 acc[8];
#pragma unroll
  for (int n = 0; n < 8; ++n) acc[n] = (f32x4)0.0f;

  const int NT = F_INDIM / 32;  // 16

  auto stageB = [&](int buf, int kt) {
#pragma unroll
    for (int i = 0; i < 2; ++i) {
      int row = wave * 32 + i * 16 + (lane >> 2);
      int g = lane & 3;
      int kg = g ^ ((row >> 1) & 3);
      const unsigned short* src = BT + (size_t)(col0 + row) * F_INDIM + kt * 32 + kg * 8;
      unsigned short* dst = &Bb[buf][(wave * 32 + i * 16) * 32];
      GLOAD_LDS16(src, dst);
    }
  };
  f32x4 ar[2];
  int arow[2], acol[2];
  auto loadA = [&](int kt) {
#pragma unroll
    for (int i = 0; i < 2; ++i) {
      int idx = wave * 512 + i * 256 + lane * 4;
      int row = idx >> 5;
      int col = idx & 31;
      arow[i] = row; acol[i] = col;
      int gr = row0 + row;
      if (gr > M - 1) gr = M - 1;
      ar[i] = *(const f32x4*)(A + (size_t)gr * F_INDIM + kt * 32 + col);
    }
  };
  auto writeA = [&](int buf) {
#pragma unroll
    for (int i = 0; i < 2; ++i) {
      int row = arow[i], col = acol[i];
      int g = col >> 3;
      int gp = g ^ ((row >> 1) & 3);
      ushort4v o;
#pragma unroll
      for (int j = 0; j < 4; ++j) o[j] = f2bf(ar[i][j]);
      *(ushort4v*)(&Ab[buf][row * 32 + gp * 8 + (col & 7)]) = o;
    }
  };
  auto compute = [&](int buf) {
    int rowA = wave * 16 + l15;
    short8 af = *(const short8*)(&Ab[buf][rowA * 32 + (l4 ^ ((rowA >> 1) & 3)) * 8]);
    short8 bf[8];
#pragma unroll
    for (int n = 0; n < 8; ++n) {
      int c = n * 16 + l15;
      bf[n] = *(const short8*)(&Bb[buf][c * 32 + (l4 ^ ((c >> 1) & 3)) * 8]);
    }
#pragma unroll
    for (int n = 0; n < 8; ++n)
      acc[n] = __builtin_amdgcn_mfma_f32_16x16x32_bf16(af, bf[n], acc[n], 0, 0, 0);
  };

  stageB(0, 0);
  loadA(0);
  writeA(0);
  __syncthreads();
#pragma unroll 4
  for (int kt = 0; kt < NT; ++kt) {
    int cur = kt & 1;
    if (kt + 1 < NT) {
      stageB(cur ^ 1, kt + 1);
      loadA(kt + 1);
    }
    compute(cur);
    if (kt + 1 < NT) writeA(cur ^ 1);
    __syncthreads();
  }

  float bv[8];
#pragma unroll
  for (int n = 0; n < 8; ++n) bv[n] = bias[col0 + n * 16 + l15];
#pragma unroll
  for (int i = 0; i < 4; ++i) {
    int grow = row0 + wave * 16 + l4 * 4 + i;
    if (grow >= M) continue;
#pragma unroll
    for (int n = 0; n < 8; ++n) {
      int gcol = col0 + n * 16 + l15;
      float v = fmaxf(acc[n][i] + bv[n], 0.0f);
      H[(size_t)grow * HID + gcol] = f2bf(v);
    }
  }
}

// ---------------- GEMM2: x0 = h @ W2 + b2 -> bf16 in group-split layout ----------------
// x0h layout: [2][N_NODES][32] ushort (group g = channels g*32..g*32+31)
__global__ __launch_bounds__(256) void gemm2_mfma(
    const unsigned short* __restrict__ Hm, const unsigned short* __restrict__ BT,
    const float* __restrict__ bias, unsigned short* __restrict__ Ch,
    int roff, int M) {
  const int t = threadIdx.x;
  const int wave = t >> 6, lane = t & 63;
  const int l15 = lane & 15, l4 = lane >> 4;
  const int row0 = blockIdx.x * 64 + wave * 16;

  f32x4 acc[4];
#pragma unroll
  for (int n = 0; n < 4; ++n) acc[n] = (f32x4)0.0f;

  int gr = row0 + l15;
  if (gr > M - 1) gr = M - 1;
  const unsigned short* arow = Hm + (size_t)gr * HID + l4 * 8;

#pragma unroll
  for (int kt = 0; kt < HID / 32; ++kt) {
    short8 af = *(const short8*)(arow + kt * 32);
    short8 bf[4];
#pragma unroll
    for (int n = 0; n < 4; ++n)
      bf[n] = *(const short8*)(BT + (size_t)(n * 16 + l15) * HID + kt * 32 + l4 * 8);
#pragma unroll
    for (int n = 0; n < 4; ++n)
      acc[n] = __builtin_amdgcn_mfma_f32_16x16x32_bf16(af, bf[n], acc[n], 0, 0, 0);
  }

#pragma unroll
  for (int n = 0; n < 4; ++n) {
    int gcol = n * 16 + l15;
    float bv = bias[gcol];
    int grp = gcol >> 5, within = gcol & 31;
#pragma unroll
    for (int i = 0; i < 4; ++i) {
      int grow = row0 + l4 * 4 + i;
      if (grow < M) {
        float v = acc[n][i] + bv;
        Ch[(size_t)grp * N_NODES * 32 + (size_t)(roff + grow) * 32 + within] = f2bf(v);
      }
    }
  }
}

// ---------------- propagation: channel-group split, L2-resident gathers --------
// z layout: [2][N_NODES][16] uint (each row = 64 B = one cache line).
// Block: group = blockIdx&1 (XCD parity), 4 nodes (one per wave).
// Wave: quarter q = lane>>4 handles edges e+4j+q; cl = lane&15 owns 2 channels.
template <bool LAST>
__global__ __launch_bounds__(256) void prop_step(
    const unsigned int* __restrict__ zin, const unsigned int* __restrict__ x0h,
    const float* __restrict__ selfw, const int* __restrict__ ptr,
    const int2* __restrict__ epack, unsigned int* __restrict__ zout,
    float* __restrict__ outf) {
  const int blk = blockIdx.x;
  const int grp = blk & 1;
  const int wid = (blk >> 1) * 4 + (threadIdx.x >> 6);
  const int lane = threadIdx.x & 63;
  if (wid >= N_NODES) return;
  const int q = lane >> 4, cl = lane & 15;
  const unsigned int* zg = zin + (size_t)grp * N_NODES * 16;

  float a0 = 0.0f, a1 = 0.0f;
  if (q == 0) {
    unsigned zs = zg[(size_t)wid * 16 + cl];
    unsigned xs = x0h[(size_t)grp * N_NODES * 16 + (size_t)wid * 16 + cl];
    float sw = selfw[wid];
    a0 = fmaf(sw, bflo(zs), ALPHA_V * bflo(xs));
    a1 = fmaf(sw, bfhi(zs), ALPHA_V * bfhi(xs));
  }

  int e = ptr[wid], e1 = ptr[wid + 1];
  for (; e + 16 <= e1; e += 16) {
    unsigned long long pp[4];
#pragma unroll
    for (int j = 0; j < 4; ++j)
      pp[j] = __builtin_nontemporal_load(
          (const unsigned long long*)(epack + e + 4 * j + q));
    unsigned g[4];
#pragma unroll
    for (int j = 0; j < 4; ++j)
      g[j] = zg[(size_t)(unsigned)pp[j] * 16 + cl];
#pragma unroll
    for (int j = 0; j < 4; ++j) {
      float w = __builtin_bit_cast(float, (unsigned)(pp[j] >> 32));
      a0 = fmaf(w, bflo(g[j]), a0);
      a1 = fmaf(w, bfhi(g[j]), a1);
    }
  }
  if (e < e1) {
    unsigned long long pp[4];
    float m[4];
#pragma unroll
    for (int j = 0; j < 4; ++j) {
      int idx = e + 4 * j + q;
      bool ok = idx < e1;
      pp[j] = __builtin_nontemporal_load(
          (const unsigned long long*)(epack + (ok ? idx : e)));
      m[j] = ok ? 1.0f : 0.0f;
    }
    unsigned g[4];
#pragma unroll
    for (int j = 0; j < 4; ++j)
      g[j] = zg[(size_t)(unsigned)pp[j] * 16 + cl];
#pragma unroll
    for (int j = 0; j < 4; ++j) {
      float w = m[j] * __builtin_bit_cast(float, (unsigned)(pp[j] >> 32));
      a0 = fmaf(w, bflo(g[j]), a0);
      a1 = fmaf(w, bfhi(g[j]), a1);
    }
  }

  a0 += __shfl_xor(a0, 16);
  a0 += __shfl_xor(a0, 32);
  a1 += __shfl_xor(a1, 16);
  a1 += __shfl_xor(a1, 32);

  if (q == 0) {
    if (LAST) {
      *(float2*)(outf + (size_t)wid * 64 + grp * 32 + 2 * cl) = make_float2(a0, a1);
    } else {
      unsigned packed = (unsigned)f2bf(a0) | ((unsigned)f2bf(a1) << 16);
      zout[(size_t)grp * N_NODES * 16 + (size_t)wid * 16 + cl] = packed;
    }
  }
}

// ---------------- host launcher ----------------
extern "C" void kernel_launch(void* const* d_in, const int* in_sizes, int n_in,
                              void* d_out, int out_size, void* d_ws, size_t ws_size,
                              hipStream_t stream) {
  const float* x  = (const float*)d_in[0];
  const float* W1 = (const float*)d_in[1];
  const float* b1 = (const float*)d_in[2];
  const float* W2 = (const float*)d_in[3];
  const float* b2 = (const float*)d_in[4];
  const int*   eb = (const int*)d_in[5];
  float* out = (float*)d_out;

  char* ws = (char*)d_ws;
  size_t off = 0;
  auto alloc = [&](size_t bytes) -> void* {
    void* p = ws + off;
    off = (off + bytes + 255) & ~(size_t)255;
    return p;
  };

  int*   flagp  = (int*)alloc(256);
  int*   cnt    = (int*)alloc(N_NODES * sizeof(int));
  int*   ptr    = (int*)alloc((N_NODES + 1) * sizeof(int));
  int*   cursor = (int*)alloc(N_NODES * sizeof(int));
  int*   bsum   = (int*)alloc(256 * sizeof(int));
  float* dinv   = (float*)alloc(N_NODES * sizeof(float));
  float* selfw  = (float*)alloc(N_NODES * sizeof(float));
  int2*  epack  = (int2*)alloc((size_t)N_EDGES * sizeof(int2));
  unsigned short* W1T = (unsigned short*)alloc((size_t)HID * F_INDIM * sizeof(unsigned short));
  unsigned short* W2T = (unsigned short*)alloc((size_t)N_CLS * HID * sizeof(unsigned short));
  unsigned int* x0h = (unsigned int*)alloc((size_t)2 * N_NODES * 16 * sizeof(unsigned int));
  unsigned int* z1  = (unsigned int*)alloc((size_t)2 * N_NODES * 16 * sizeof(unsigned int));
  unsigned int* z2  = (unsigned int*)alloc((size_t)2 * N_NODES * 16 * sizeof(unsigned int));

  int nchunks = 1;
  while (nchunks < 16) {
    size_t hbytes = (size_t)(N_NODES / nchunks) * HID * sizeof(unsigned short);
    if (off + hbytes <= ws_size) break;
    nchunks <<= 1;
  }
  int Mc = N_NODES / nchunks;
  unsigned short* h = (unsigned short*)alloc((size_t)Mc * HID * sizeof(unsigned short));

  hipMemsetAsync(cnt, 0, N_NODES * sizeof(int), stream);
  detect_kernel<<<1, 256, 0, stream>>>(eb, flagp);
  count_kernel<<<(N_EDGES + 255) / 256, 256, 0, stream>>>(eb, flagp, cnt);
  int nblk = (N_NODES + 255) / 256;
  scan1_kernel<<<nblk, 256, 0, stream>>>(cnt, ptr, bsum);
  scan2_kernel<<<1, 256, 0, stream>>>(bsum, nblk);
  scan3_kernel<<<nblk, 256, 0, stream>>>(ptr, bsum);
  dinv_kernel<<<nblk, 256, 0, stream>>>(cnt, ptr, dinv, selfw, cursor);
  fill_kernel<<<(N_EDGES + 255) / 256, 256, 0, stream>>>(eb, flagp, dinv, cursor, epack);
  prep_w<<<(F_INDIM * HID + HID * N_CLS + 255) / 256, 256, 0, stream>>>(W1, W2, W1T, W2T);

  for (int ci = 0; ci < nchunks; ++ci) {
    const float* Achunk = x + (size_t)ci * Mc * F_INDIM;
    dim3 g1((Mc + 63) / 64, HID / 128);
    gemm1_mfma<<<g1, 256, 0, stream>>>(Achunk, W1T, b1, h, Mc);
    dim3 g2((Mc + 63) / 64, 1);
    gemm2_mfma<<<g2, 256, 0, stream>>>(h, W2T, b2,
        (unsigned short*)x0h, ci * Mc, Mc);
  }

  int pgrid = 2 * ((N_NODES + 3) / 4);  // group-parity blocks, 4 nodes/block
  const unsigned int* zin = x0h;
  unsigned int* zo[2] = {z1, z2};
  for (int s = 0; s < K_STEPS - 1; ++s) {
    unsigned int* zout = zo[s & 1];
    prop_step<false><<<pgrid, 256, 0, stream>>>(zin, x0h, selfw, ptr, epack, zout, nullptr);
    zin = zout;
  }
  prop_step<true><<<pgrid, 256, 0, stream>>>(zin, x0h, selfw, ptr, epack, nullptr, out);
}

// Round 6
// 454.111 us; speedup vs baseline: 1.3483x; 1.3483x over previous
//
#include <hip/hip_runtime.h>

#define N_NODES 50000
#define N_EDGES 800000
#define F_INDIM 512
#define HID     256
#define N_CLS   64
#define K_STEPS 10
#define ALPHA_V 0.1f

#define NPB 28     // nodes per prop block (4 waves x 7)
#define NPW 7
#define ECAP 1536  // LDS edge-record capacity (mean 448, 12 KB)

typedef __attribute__((ext_vector_type(8))) short short8;
typedef __attribute__((ext_vector_type(4))) float f32x4;

__device__ __forceinline__ unsigned short f2bf(float f) {
  unsigned u = __builtin_bit_cast(unsigned, f);
  unsigned r = (u + 0x7fffu + ((u >> 16) & 1u)) >> 16;
  return (unsigned short)r;
}
__device__ __forceinline__ float bflo(unsigned g) {
  return __builtin_bit_cast(float, g << 16);
}
__device__ __forceinline__ float bfhi(unsigned g) {
  return __builtin_bit_cast(float, g & 0xffff0000u);
}

// ---------------- edge dtype detection ----------------
__global__ void detect_kernel(const int* __restrict__ eb, int* __restrict__ flag) {
  __shared__ int any;
  if (threadIdx.x == 0) any = 0;
  __syncthreads();
  for (int j = threadIdx.x; j < 1024; j += 256) {
    if (eb[2 * j + 1] != 0) atomicOr(&any, 1);
  }
  __syncthreads();
  if (threadIdx.x == 0) flag[0] = any ? 0 : 1;  // 1 => int64 stride, 0 => int32
}

// ---------------- degree histogram over targets ----------------
__global__ void count_kernel(const int* __restrict__ eb, const int* __restrict__ flagp,
                             int* __restrict__ cnt) {
  int e = blockIdx.x * 256 + threadIdx.x;
  if (e >= N_EDGES) return;
  int sh = flagp[0];
  int c = eb[((size_t)(N_EDGES + e)) << sh];
  atomicAdd(&cnt[c], 1);
}

// ---------------- 3-kernel exclusive scan ----------------
__global__ void scan1_kernel(const int* __restrict__ cnt, int* __restrict__ ptr,
                             int* __restrict__ bsum) {
  __shared__ int sm[256];
  int t = threadIdx.x;
  int i = blockIdx.x * 256 + t;
  int v = (i < N_NODES) ? cnt[i] : 0;
  sm[t] = v;
  __syncthreads();
  for (int off = 1; off < 256; off <<= 1) {
    int x = sm[t];
    if (t >= off) x += sm[t - off];
    __syncthreads();
    sm[t] = x;
    __syncthreads();
  }
  int incl = sm[t];
  if (i < N_NODES) ptr[i] = incl - v;
  if (t == 255) bsum[blockIdx.x] = incl;
}

__global__ void scan2_kernel(int* __restrict__ bsum, int nblk) {
  __shared__ int sm[256];
  int t = threadIdx.x;
  int v = (t < nblk) ? bsum[t] : 0;
  sm[t] = v;
  __syncthreads();
  for (int off = 1; off < 256; off <<= 1) {
    int x = sm[t];
    if (t >= off) x += sm[t - off];
    __syncthreads();
    sm[t] = x;
    __syncthreads();
  }
  int incl = sm[t];
  if (t < nblk) bsum[t] = incl - v;
}

__global__ void scan3_kernel(int* __restrict__ ptr, const int* __restrict__ bsum) {
  int i = blockIdx.x * 256 + threadIdx.x;
  if (i < N_NODES) ptr[i] += bsum[i >> 8];
  if (i == 0) ptr[N_NODES] = N_EDGES;
}

// ---------------- dinv + selfw + cursor init ----------------
__global__ void dinv_kernel(const int* __restrict__ cnt, const int* __restrict__ ptr,
                            float* __restrict__ dinv, float* __restrict__ selfw,
                            int* __restrict__ cursor) {
  int i = blockIdx.x * 256 + threadIdx.x;
  if (i >= N_NODES) return;
  float di = rsqrtf((float)cnt[i] + 1.0f);
  dinv[i] = di;
  selfw[i] = (1.0f - ALPHA_V) * di * di;
  cursor[i] = ptr[i];
}

// ---------------- CSR fill (by target), packed (src, weight) ----------------
__global__ void fill_kernel(const int* __restrict__ eb, const int* __restrict__ flagp,
                            const float* __restrict__ dinv, int* __restrict__ cursor,
                            int2* __restrict__ epack) {
  int e = blockIdx.x * 256 + threadIdx.x;
  if (e >= N_EDGES) return;
  int sh = flagp[0];
  int r = eb[((size_t)e) << sh];
  int c = eb[((size_t)(N_EDGES + e)) << sh];
  int pos = atomicAdd(&cursor[c], 1);
  float w = (1.0f - ALPHA_V) * dinv[r] * dinv[c];
  epack[pos] = make_int2(r, __float_as_int(w));
}

// ---------------- weight transpose + bf16 prepass ----------------
__global__ void prep_w(const float* __restrict__ W1, const float* __restrict__ W2,
                       unsigned short* __restrict__ W1T, unsigned short* __restrict__ W2T) {
  int i = blockIdx.x * 256 + threadIdx.x;
  if (i < F_INDIM * HID) {
    int k = i >> 8, c = i & 255;
    W1T[(size_t)c * F_INDIM + k] = f2bf(W1[i]);
  }
  int j = i - F_INDIM * HID;
  if (j >= 0 && j < HID * N_CLS) {
    int k = j >> 6, c = j & 63;
    W2T[(size_t)c * HID + k] = f2bf(W2[j]);
  }
}

// ---------------- GEMM1: h = relu(x @ W1 + b1), bf16 MFMA, no LDS/barriers ----
// Wave owns 16 rows x 128 cols. A fragments loaded direct fp32->bf16 in-reg;
// B fragments direct from W1T (L2-resident 256 KB). Fully unrolled K, zero
// __syncthreads -> compiler/HW pipelines loads across the 16 K-tiles.
__global__ __launch_bounds__(256) void gemm1_mfma(
    const float* __restrict__ A, const unsigned short* __restrict__ BT,
    const float* __restrict__ bias, unsigned short* __restrict__ H, int M) {
  const int tid = threadIdx.x;
  const int wv = tid >> 6, lane = tid & 63;
  const int l15 = lane & 15, l4 = lane >> 4;
  const int row0 = blockIdx.x * 64 + wv * 16;
  const int col0 = blockIdx.y * 128;

  f32x4 acc[8];
#pragma unroll
  for (int n = 0; n < 8; ++n) acc[n] = (f32x4)0.0f;

  int gr = row0 + l15;
  if (gr > M - 1) gr = M - 1;
  const float* arow = A + (size_t)gr * F_INDIM + l4 * 8;
  const unsigned short* bbase = BT + (size_t)(col0 + l15) * F_INDIM + l4 * 8;

#pragma unroll
  for (int kt = 0; kt < F_INDIM / 32; ++kt) {  // 16 K-tiles of 32
    f32x4 a0 = *(const f32x4*)(arow + kt * 32);
    f32x4 a1 = *(const f32x4*)(arow + kt * 32 + 4);
    short8 bf[8];
#pragma unroll
    for (int n = 0; n < 8; ++n)
      bf[n] = *(const short8*)(bbase + (size_t)n * 16 * F_INDIM + kt * 32);
    short8 af;
#pragma unroll
    for (int j = 0; j < 4; ++j) {
      af[j] = (short)f2bf(a0[j]);
      af[4 + j] = (short)f2bf(a1[j]);
    }
#pragma unroll
    for (int n = 0; n < 8; ++n)
      acc[n] = __builtin_amdgcn_mfma_f32_16x16x32_bf16(af, bf[n], acc[n], 0, 0, 0);
  }

  float bv[8];
#pragma unroll
  for (int n = 0; n < 8; ++n) bv[n] = bias[col0 + n * 16 + l15];
#pragma unroll
  for (int i = 0; i < 4; ++i) {
    int grow = row0 + l4 * 4 + i;
    if (grow >= M) continue;
#pragma unroll
    for (int n = 0; n < 8; ++n) {
      int gcol = col0 + n * 16 + l15;
      float v = fmaxf(acc[n][i] + bv[n], 0.0f);
      H[(size_t)grow * HID + gcol] = f2bf(v);
    }
  }
}

// ---------------- GEMM2: x0 = h @ W2 + b2 -> bf16 flat [N][64] ----------------
__global__ __launch_bounds__(256) void gemm2_mfma(
    const unsigned short* __restrict__ Hm, const unsigned short* __restrict__ BT,
    const float* __restrict__ bias, unsigned short* __restrict__ Ch,
    int roff, int M) {
  const int t = threadIdx.x;
  const int wave = t >> 6, lane = t & 63;
  const int l15 = lane & 15, l4 = lane >> 4;
  const int row0 = blockIdx.x * 64 + wave * 16;

  f32x4 acc[4];
#pragma unroll
  for (int n = 0; n < 4; ++n) acc[n] = (f32x4)0.0f;

  int gr = row0 + l15;
  if (gr > M - 1) gr = M - 1;
  const unsigned short* arow = Hm + (size_t)gr * HID + l4 * 8;

#pragma unroll
  for (int kt = 0; kt < HID / 32; ++kt) {
    short8 af = *(const short8*)(arow + kt * 32);
    short8 bf[4];
#pragma unroll
    for (int n = 0; n < 4; ++n)
      bf[n] = *(const short8*)(BT + (size_t)(n * 16 + l15) * HID + kt * 32 + l4 * 8);
#pragma unroll
    for (int n = 0; n < 4; ++n)
      acc[n] = __builtin_amdgcn_mfma_f32_16x16x32_bf16(af, bf[n], acc[n], 0, 0, 0);
  }

#pragma unroll
  for (int n = 0; n < 4; ++n) {
    int gcol = n * 16 + l15;
    float bv = bias[gcol];
#pragma unroll
    for (int i = 0; i < 4; ++i) {
      int grow = row0 + l4 * 4 + i;
      if (grow < M) {
        float v = acc[n][i] + bv;
        Ch[(size_t)(roff + grow) * N_CLS + gcol] = f2bf(v);
      }
    }
  }
}

// ---------------- propagation: LDS-cached CSR slice per block ----------------
// Block owns 28 consecutive nodes; bulk-loads their edge records into LDS once.
// Wave = 7 nodes; lane half (32) handles alternating edges, cl owns 2 channels
// of the 128-B bf16 z row; fp32 accumulate; shfl_xor(32) combine.
template <bool LAST>
__global__ __launch_bounds__(256) void prop_step(
    const unsigned int* __restrict__ zin, const unsigned int* __restrict__ x0h,
    const float* __restrict__ selfw, const int* __restrict__ ptr,
    const int2* __restrict__ epack, unsigned int* __restrict__ zout,
    float* __restrict__ outf) {
  __shared__ int2 erec[ECAP];
  __shared__ int lptr[NPB + 1];
  __shared__ float lsw[NPB];

  const int tid = threadIdx.x;
  const int n0 = blockIdx.x * NPB;
  int nEnd = N_NODES - n0;
  if (nEnd > NPB) nEnd = NPB;

  if (tid <= nEnd) lptr[tid] = ptr[n0 + tid];
  if (tid < nEnd) lsw[tid] = selfw[n0 + tid];
  __syncthreads();
  const int base = lptr[0];
  const int cnt = lptr[nEnd] - base;
  for (int i = tid; i < cnt && i < ECAP; i += 256) erec[i] = epack[base + i];
  __syncthreads();

  const int wv = tid >> 6, lane = tid & 63;
  const int half = lane >> 5, cl = lane & 31;

  auto run = [&](auto getrec) {
    for (int ni = wv * NPW; ni < wv * NPW + NPW; ++ni) {
      if (ni >= nEnd) break;
      const int node = n0 + ni;
      float a0 = 0.0f, a1 = 0.0f;
      if (half == 0) {
        unsigned zs = zin[(size_t)node * 32 + cl];
        unsigned xs = x0h[(size_t)node * 32 + cl];
        float sw = lsw[ni];
        a0 = fmaf(sw, bflo(zs), ALPHA_V * bflo(xs));
        a1 = fmaf(sw, bfhi(zs), ALPHA_V * bfhi(xs));
      }
      int e = lptr[ni] - base, e1 = lptr[ni + 1] - base;
      for (; e + 16 <= e1; e += 16) {
        int2 p[8];
#pragma unroll
        for (int j = 0; j < 8; ++j) p[j] = getrec(e + 2 * j + half);
        unsigned g[8];
#pragma unroll
        for (int j = 0; j < 8; ++j) g[j] = zin[(size_t)p[j].x * 32 + cl];
#pragma unroll
        for (int j = 0; j < 8; ++j) {
          float w = __int_as_float(p[j].y);
          a0 = fmaf(w, bflo(g[j]), a0);
          a1 = fmaf(w, bfhi(g[j]), a1);
        }
      }
      if (e < e1) {
        int2 p[8];
        float m[8];
#pragma unroll
        for (int j = 0; j < 8; ++j) {
          int gi = e + 2 * j + half;
          bool ok = gi < e1;
          p[j] = getrec(ok ? gi : e);
          m[j] = ok ? 1.0f : 0.0f;
        }
        unsigned g[8];
#pragma unroll
        for (int j = 0; j < 8; ++j) g[j] = zin[(size_t)p[j].x * 32 + cl];
#pragma unroll
        for (int j = 0; j < 8; ++j) {
          float w = m[j] * __int_as_float(p[j].y);
          a0 = fmaf(w, bflo(g[j]), a0);
          a1 = fmaf(w, bfhi(g[j]), a1);
        }
      }
      a0 += __shfl_xor(a0, 32);
      a1 += __shfl_xor(a1, 32);
      if (half == 0) {
        if (LAST) {
          *(float2*)(outf + (size_t)node * 64 + 2 * cl) = make_float2(a0, a1);
        } else {
          zout[(size_t)node * 32 + cl] =
              (unsigned)f2bf(a0) | ((unsigned)f2bf(a1) << 16);
        }
      }
    }
  };

  if (cnt <= ECAP) {
    run([&](int i) { return erec[i]; });
  } else {
    run([&](int i) { return epack[base + i]; });  // fallback (≈never)
  }
}

// ---------------- host launcher ----------------
extern "C" void kernel_launch(void* const* d_in, const int* in_sizes, int n_in,
                              void* d_out, int out_size, void* d_ws, size_t ws_size,
                              hipStream_t stream) {
  const float* x  = (const float*)d_in[0];
  const float* W1 = (const float*)d_in[1];
  const float* b1 = (const float*)d_in[2];
  const float* W2 = (const float*)d_in[3];
  const float* b2 = (const float*)d_in[4];
  const int*   eb = (const int*)d_in[5];
  float* out = (float*)d_out;

  char* ws = (char*)d_ws;
  size_t off = 0;
  auto alloc = [&](size_t bytes) -> void* {
    void* p = ws + off;
    off = (off + bytes + 255) & ~(size_t)255;
    return p;
  };

  int*   flagp  = (int*)alloc(256);
  int*   cnt    = (int*)alloc(N_NODES * sizeof(int));
  int*   ptr    = (int*)alloc((N_NODES + 1) * sizeof(int));
  int*   cursor = (int*)alloc(N_NODES * sizeof(int));
  int*   bsum   = (int*)alloc(256 * sizeof(int));
  float* dinv   = (float*)alloc(N_NODES * sizeof(float));
  float* selfw  = (float*)alloc(N_NODES * sizeof(float));
  int2*  epack  = (int2*)alloc((size_t)N_EDGES * sizeof(int2));
  unsigned short* W1T = (unsigned short*)alloc((size_t)HID * F_INDIM * sizeof(unsigned short));
  unsigned short* W2T = (unsigned short*)alloc((size_t)N_CLS * HID * sizeof(unsigned short));
  unsigned int* x0h = (unsigned int*)alloc((size_t)N_NODES * 32 * sizeof(unsigned int));
  unsigned int* z1  = (unsigned int*)alloc((size_t)N_NODES * 32 * sizeof(unsigned int));
  unsigned int* z2  = (unsigned int*)alloc((size_t)N_NODES * 32 * sizeof(unsigned int));

  int nchunks = 1;
  while (nchunks < 16) {
    size_t hbytes = (size_t)(N_NODES / nchunks) * HID * sizeof(unsigned short);
    if (off + hbytes <= ws_size) break;
    nchunks <<= 1;
  }
  int Mc = N_NODES / nchunks;
  unsigned short* h = (unsigned short*)alloc((size_t)Mc * HID * sizeof(unsigned short));

  hipMemsetAsync(cnt, 0, N_NODES * sizeof(int), stream);
  detect_kernel<<<1, 256, 0, stream>>>(eb, flagp);
  count_kernel<<<(N_EDGES + 255) / 256, 256, 0, stream>>>(eb, flagp, cnt);
  int nblk = (N_NODES + 255) / 256;
  scan1_kernel<<<nblk, 256, 0, stream>>>(cnt, ptr, bsum);
  scan2_kernel<<<1, 256, 0, stream>>>(bsum, nblk);
  scan3_kernel<<<nblk, 256, 0, stream>>>(ptr, bsum);
  dinv_kernel<<<nblk, 256, 0, stream>>>(cnt, ptr, dinv, selfw, cursor);
  fill_kernel<<<(N_EDGES + 255) / 256, 256, 0, stream>>>(eb, flagp, dinv, cursor, epack);
  prep_w<<<(F_INDIM * HID + HID * N_CLS + 255) / 256, 256, 0, stream>>>(W1, W2, W1T, W2T);

  for (int ci = 0; ci < nchunks; ++ci) {
    const float* Achunk = x + (size_t)ci * Mc * F_INDIM;
    dim3 g1((Mc + 63) / 64, HID / 128);
    gemm1_mfma<<<g1, 256, 0, stream>>>(Achunk, W1T, b1, h, Mc);
    dim3 g2((Mc + 63) / 64, 1);
    gemm2_mfma<<<g2, 256, 0, stream>>>(h, W2T, b2,
        (unsigned short*)x0h, ci * Mc, Mc);
  }

  int pgrid = (N_NODES + NPB - 1) / NPB;  // 1786
  const unsigned int* zin = x0h;
  unsigned int* zo[2] = {z1, z2};
  for (int s = 0; s < K_STEPS - 1; ++s) {
    unsigned int* zout = zo[s & 1];
    prop_step<false><<<pgrid, 256, 0, stream>>>(zin, x0h, selfw, ptr, epack, zout, nullptr);
    zin = zout;
  }
  prop_step<true><<<pgrid, 256, 0, stream>>>(zin, x0h, selfw, ptr, epack, nullptr, out);
}

// Round 7
// 443.967 us; speedup vs baseline: 1.3791x; 1.0228x over previous
//
#include <hip/hip_runtime.h>

#define N_NODES 50000
#define N_EDGES 800000
#define F_INDIM 512
#define HID     256
#define N_CLS   64
#define K_STEPS 10
#define ALPHA_V 0.1f

#define NPB 32     // nodes per prop block (4 waves x 8)
#define ECAP 1280  // LDS edge-record capacity (mean 512, 10 KB)

typedef __attribute__((ext_vector_type(8))) short short8;
typedef __attribute__((ext_vector_type(4))) float f32x4;
typedef __attribute__((ext_vector_type(4))) unsigned short ushort4v;

__device__ __forceinline__ unsigned short f2bf(float f) {
  unsigned u = __builtin_bit_cast(unsigned, f);
  unsigned r = (u + 0x7fffu + ((u >> 16) & 1u)) >> 16;
  return (unsigned short)r;
}
__device__ __forceinline__ float bflo(unsigned g) {
  return __builtin_bit_cast(float, g << 16);
}
__device__ __forceinline__ float bfhi(unsigned g) {
  return __builtin_bit_cast(float, g & 0xffff0000u);
}

#define GLOAD_LDS16(g, l)                                                        \
  __builtin_amdgcn_global_load_lds(                                              \
      (const __attribute__((address_space(1))) unsigned int*)(g),                \
      (__attribute__((address_space(3))) unsigned int*)(l), 16, 0, 0)

// ---------------- edge dtype detection ----------------
__global__ void detect_kernel(const int* __restrict__ eb, int* __restrict__ flag) {
  __shared__ int any;
  if (threadIdx.x == 0) any = 0;
  __syncthreads();
  for (int j = threadIdx.x; j < 1024; j += 256) {
    if (eb[2 * j + 1] != 0) atomicOr(&any, 1);
  }
  __syncthreads();
  if (threadIdx.x == 0) flag[0] = any ? 0 : 1;  // 1 => int64 stride, 0 => int32
}

// ---------------- degree histogram over targets ----------------
__global__ void count_kernel(const int* __restrict__ eb, const int* __restrict__ flagp,
                             int* __restrict__ cnt) {
  int e = blockIdx.x * 256 + threadIdx.x;
  if (e >= N_EDGES) return;
  int sh = flagp[0];
  int c = eb[((size_t)(N_EDGES + e)) << sh];
  atomicAdd(&cnt[c], 1);
}

// ---------------- 3-kernel exclusive scan ----------------
__global__ void scan1_kernel(const int* __restrict__ cnt, int* __restrict__ ptr,
                             int* __restrict__ bsum) {
  __shared__ int sm[256];
  int t = threadIdx.x;
  int i = blockIdx.x * 256 + t;
  int v = (i < N_NODES) ? cnt[i] : 0;
  sm[t] = v;
  __syncthreads();
  for (int off = 1; off < 256; off <<= 1) {
    int x = sm[t];
    if (t >= off) x += sm[t - off];
    __syncthreads();
    sm[t] = x;
    __syncthreads();
  }
  int incl = sm[t];
  if (i < N_NODES) ptr[i] = incl - v;
  if (t == 255) bsum[blockIdx.x] = incl;
}

__global__ void scan2_kernel(int* __restrict__ bsum, int nblk) {
  __shared__ int sm[256];
  int t = threadIdx.x;
  int v = (t < nblk) ? bsum[t] : 0;
  sm[t] = v;
  __syncthreads();
  for (int off = 1; off < 256; off <<= 1) {
    int x = sm[t];
    if (t >= off) x += sm[t - off];
    __syncthreads();
    sm[t] = x;
    __syncthreads();
  }
  int incl = sm[t];
  if (t < nblk) bsum[t] = incl - v;
}

__global__ void scan3_kernel(int* __restrict__ ptr, const int* __restrict__ bsum) {
  int i = blockIdx.x * 256 + threadIdx.x;
  if (i < N_NODES) ptr[i] += bsum[i >> 8];
  if (i == 0) ptr[N_NODES] = N_EDGES;
}

// ---------------- dinv + selfw + cursor init ----------------
__global__ void dinv_kernel(const int* __restrict__ cnt, const int* __restrict__ ptr,
                            float* __restrict__ dinv, float* __restrict__ selfw,
                            int* __restrict__ cursor) {
  int i = blockIdx.x * 256 + threadIdx.x;
  if (i >= N_NODES) return;
  float di = rsqrtf((float)cnt[i] + 1.0f);
  dinv[i] = di;
  selfw[i] = (1.0f - ALPHA_V) * di * di;
  cursor[i] = ptr[i];
}

// ---------------- CSR fill (by target), packed (src, weight) ----------------
__global__ void fill_kernel(const int* __restrict__ eb, const int* __restrict__ flagp,
                            const float* __restrict__ dinv, int* __restrict__ cursor,
                            int2* __restrict__ epack) {
  int e = blockIdx.x * 256 + threadIdx.x;
  if (e >= N_EDGES) return;
  int sh = flagp[0];
  int r = eb[((size_t)e) << sh];
  int c = eb[((size_t)(N_EDGES + e)) << sh];
  int pos = atomicAdd(&cursor[c], 1);
  float w = (1.0f - ALPHA_V) * dinv[r] * dinv[c];
  epack[pos] = make_int2(r, __float_as_int(w));
}

// ---------------- weight transpose + bf16 prepass ----------------
__global__ void prep_w(const float* __restrict__ W1, const float* __restrict__ W2,
                       unsigned short* __restrict__ W1T, unsigned short* __restrict__ W2T) {
  int i = blockIdx.x * 256 + threadIdx.x;
  if (i < F_INDIM * HID) {
    int k = i >> 8, c = i & 255;
    W1T[(size_t)c * F_INDIM + k] = f2bf(W1[i]);
  }
  int j = i - F_INDIM * HID;
  if (j >= 0 && j < HID * N_CLS) {
    int k = j >> 6, c = j & 63;
    W2T[(size_t)c * HID + k] = f2bf(W2[j]);
  }
}

// ---------------- GEMM1 (round-4 version): BM=64 BN=128 BK=32, LDS dbuf ------
__global__ __launch_bounds__(256, 4) void gemm1_mfma(
    const float* __restrict__ A, const unsigned short* __restrict__ BT,
    const float* __restrict__ bias, unsigned short* __restrict__ H, int M) {
  __shared__ unsigned short Ab[2][64 * 32];    // 4 KB each
  __shared__ unsigned short Bb[2][128 * 32];   // 8 KB each
  const int t = threadIdx.x;
  const int wave = t >> 6, lane = t & 63;
  const int l15 = lane & 15, l4 = lane >> 4;
  const int row0 = blockIdx.x * 64, col0 = blockIdx.y * 128;

  f32x4 acc[8];
#pragma unroll
  for (int n = 0; n < 8; ++n) acc[n] = (f32x4)0.0f;

  const int NT = F_INDIM / 32;  // 16

  auto stageB = [&](int buf, int kt) {
#pragma unroll
    for (int i = 0; i < 2; ++i) {
      int row = wave * 32 + i * 16 + (lane >> 2);
      int g = lane & 3;
      int kg = g ^ ((row >> 1) & 3);
      const unsigned short* src = BT + (size_t)(col0 + row) * F_INDIM + kt * 32 + kg * 8;
      unsigned short* dst = &Bb[buf][(wave * 32 + i * 16) * 32];
      GLOAD_LDS16(src, dst);
    }
  };
  f32x4 ar[2];
  int arow[2], acol[2];
  auto loadA = [&](int kt) {
#pragma unroll
    for (int i = 0; i < 2; ++i) {
      int idx = wave * 512 + i * 256 + lane * 4;
      int row = idx >> 5;
      int col = idx & 31;
      arow[i] = row; acol[i] = col;
      int gr = row0 + row;
      if (gr > M - 1) gr = M - 1;
      ar[i] = *(const f32x4*)(A + (size_t)gr * F_INDIM + kt * 32 + col);
    }
  };
  auto writeA = [&](int buf) {
#pragma unroll
    for (int i = 0; i < 2; ++i) {
      int row = arow[i], col = acol[i];
      int g = col >> 3;
      int gp = g ^ ((row >> 1) & 3);
      ushort4v o;
#pragma unroll
      for (int j = 0; j < 4; ++j) o[j] = f2bf(ar[i][j]);
      *(ushort4v*)(&Ab[buf][row * 32 + gp * 8 + (col & 7)]) = o;
    }
  };
  auto compute = [&](int buf) {
    int rowA = wave * 16 + l15;
    short8 af = *(const short8*)(&Ab[buf][rowA * 32 + (l4 ^ ((rowA >> 1) & 3)) * 8]);
    short8 bf[8];
#pragma unroll
    for (int n = 0; n < 8; ++n) {
      int c = n * 16 + l15;
      bf[n] = *(const short8*)(&Bb[buf][c * 32 + (l4 ^ ((c >> 1) & 3)) * 8]);
    }
#pragma unroll
    for (int n = 0; n < 8; ++n)
      acc[n] = __builtin_amdgcn_mfma_f32_16x16x32_bf16(af, bf[n], acc[n], 0, 0, 0);
  };

  stageB(0, 0);
  loadA(0);
  writeA(0);
  __syncthreads();
#pragma unroll 4
  for (int kt = 0; kt < NT; ++kt) {
    int cur = kt & 1;
    if (kt + 1 < NT) {
      stageB(cur ^ 1, kt + 1);
      loadA(kt + 1);
    }
    compute(cur);
    if (kt + 1 < NT) writeA(cur ^ 1);
    __syncthreads();
  }

  float bv[8];
#pragma unroll
  for (int n = 0; n < 8; ++n) bv[n] = bias[col0 + n * 16 + l15];
#pragma unroll
  for (int i = 0; i < 4; ++i) {
    int grow = row0 + wave * 16 + l4 * 4 + i;
    if (grow >= M) continue;
#pragma unroll
    for (int n = 0; n < 8; ++n) {
      int gcol = col0 + n * 16 + l15;
      float v = fmaxf(acc[n][i] + bv[n], 0.0f);
      H[(size_t)grow * HID + gcol] = f2bf(v);
    }
  }
}

// ---------------- GEMM2: x0 = h @ W2 + b2 -> bf16 flat [N][64] ----------------
__global__ __launch_bounds__(256) void gemm2_mfma(
    const unsigned short* __restrict__ Hm, const unsigned short* __restrict__ BT,
    const float* __restrict__ bias, unsigned short* __restrict__ Ch,
    int roff, int M) {
  const int t = threadIdx.x;
  const int wave = t >> 6, lane = t & 63;
  const int l15 = lane & 15, l4 = lane >> 4;
  const int row0 = blockIdx.x * 64 + wave * 16;

  f32x4 acc[4];
#pragma unroll
  for (int n = 0; n < 4; ++n) acc[n] = (f32x4)0.0f;

  int gr = row0 + l15;
  if (gr > M - 1) gr = M - 1;
  const unsigned short* arow = Hm + (size_t)gr * HID + l4 * 8;

#pragma unroll
  for (int kt = 0; kt < HID / 32; ++kt) {
    short8 af = *(const short8*)(arow + kt * 32);
    short8 bf[4];
#pragma unroll
    for (int n = 0; n < 4; ++n)
      bf[n] = *(const short8*)(BT + (size_t)(n * 16 + l15) * HID + kt * 32 + l4 * 8);
#pragma unroll
    for (int n = 0; n < 4; ++n)
      acc[n] = __builtin_amdgcn_mfma_f32_16x16x32_bf16(af, bf[n], acc[n], 0, 0, 0);
  }

#pragma unroll
  for (int n = 0; n < 4; ++n) {
    int gcol = n * 16 + l15;
    float bv = bias[gcol];
#pragma unroll
    for (int i = 0; i < 4; ++i) {
      int grow = row0 + l4 * 4 + i;
      if (grow < M) {
        float v = acc[n][i] + bv;
        Ch[(size_t)(roff + grow) * N_CLS + gcol] = f2bf(v);
      }
    }
  }
}

// ---------------- propagation: LDS CSR slice + node-paired gathers ------------
// Block owns 32 nodes (bulk edge records in LDS). Wave = 8 nodes as 4 pairs;
// each pair's batch issues 16 gather instrs in flight (8 per node).
template <bool LAST>
__global__ __launch_bounds__(256) void prop_step(
    const unsigned int* __restrict__ zin, const unsigned int* __restrict__ x0h,
    const float* __restrict__ selfw, const int* __restrict__ ptr,
    const int2* __restrict__ epack, unsigned int* __restrict__ zout,
    float* __restrict__ outf) {
  __shared__ int2 erec[ECAP];
  __shared__ int lptr[NPB + 1];
  __shared__ float lsw[NPB];

  const int tid = threadIdx.x;
  const int n0 = blockIdx.x * NPB;
  int nEnd = N_NODES - n0;
  if (nEnd > NPB) nEnd = NPB;

  if (tid <= nEnd) lptr[tid] = ptr[n0 + tid];
  if (tid < nEnd) lsw[tid] = selfw[n0 + tid];
  __syncthreads();
  const int base = lptr[0];
  const int cnt = lptr[nEnd] - base;
  for (int i = tid; i < cnt && i < ECAP; i += 256) erec[i] = epack[base + i];
  __syncthreads();

  const int wv = tid >> 6, lane = tid & 63;
  const int half = lane >> 5, cl = lane & 31;

  auto proc = [&](auto getrec) {
    for (int pi = 0; pi < 4; ++pi) {
      const int niA = wv * 8 + pi * 2;
      if (niA >= nEnd) break;
      const int niB = niA + 1;
      const bool hasB = niB < nEnd;
      const int nodeA = n0 + niA, nodeB = n0 + niB;

      float aA0 = 0.f, aA1 = 0.f, aB0 = 0.f, aB1 = 0.f;
      if (half == 0) {
        unsigned zs = zin[(size_t)nodeA * 32 + cl];
        unsigned xs = x0h[(size_t)nodeA * 32 + cl];
        float sw = lsw[niA];
        aA0 = fmaf(sw, bflo(zs), ALPHA_V * bflo(xs));
        aA1 = fmaf(sw, bfhi(zs), ALPHA_V * bfhi(xs));
        if (hasB) {
          unsigned zsB = zin[(size_t)nodeB * 32 + cl];
          unsigned xsB = x0h[(size_t)nodeB * 32 + cl];
          float swB = lsw[niB];
          aB0 = fmaf(swB, bflo(zsB), ALPHA_V * bflo(xsB));
          aB1 = fmaf(swB, bfhi(zsB), ALPHA_V * bfhi(xsB));
        }
      }

      int eA = lptr[niA] - base;
      const int eA1 = lptr[niA + 1] - base;
      int eB = hasB ? (lptr[niB] - base) : 0;
      const int eB1 = hasB ? (lptr[niB + 1] - base) : 0;

      while (eA < eA1 || eB < eB1) {
        int2 p[16];
        float m[16];
#pragma unroll
        for (int j = 0; j < 8; ++j) {
          int gi = eA + 2 * j + half;
          bool ok = gi < eA1;
          p[j] = getrec(ok ? gi : (eA < eA1 ? eA : 0));
          m[j] = ok ? 1.0f : 0.0f;
        }
#pragma unroll
        for (int j = 0; j < 8; ++j) {
          int gi = eB + 2 * j + half;
          bool ok = gi < eB1;
          p[8 + j] = getrec(ok ? gi : (eB < eB1 ? eB : 0));
          m[8 + j] = ok ? 1.0f : 0.0f;
        }
        unsigned g[16];
#pragma unroll
        for (int j = 0; j < 16; ++j) g[j] = zin[(size_t)p[j].x * 32 + cl];
#pragma unroll
        for (int j = 0; j < 8; ++j) {
          float w = m[j] * __int_as_float(p[j].y);
          aA0 = fmaf(w, bflo(g[j]), aA0);
          aA1 = fmaf(w, bfhi(g[j]), aA1);
        }
#pragma unroll
        for (int j = 0; j < 8; ++j) {
          float w = m[8 + j] * __int_as_float(p[8 + j].y);
          aB0 = fmaf(w, bflo(g[8 + j]), aB0);
          aB1 = fmaf(w, bfhi(g[8 + j]), aB1);
        }
        eA += 16; if (eA > eA1) eA = eA1;
        eB += 16; if (eB > eB1) eB = eB1;
      }

      aA0 += __shfl_xor(aA0, 32);
      aA1 += __shfl_xor(aA1, 32);
      aB0 += __shfl_xor(aB0, 32);
      aB1 += __shfl_xor(aB1, 32);

      if (half == 0) {
        if (LAST) {
          *(float2*)(outf + (size_t)nodeA * 64 + 2 * cl) = make_float2(aA0, aA1);
          if (hasB)
            *(float2*)(outf + (size_t)nodeB * 64 + 2 * cl) = make_float2(aB0, aB1);
        } else {
          zout[(size_t)nodeA * 32 + cl] =
              (unsigned)f2bf(aA0) | ((unsigned)f2bf(aA1) << 16);
          if (hasB)
            zout[(size_t)nodeB * 32 + cl] =
                (unsigned)f2bf(aB0) | ((unsigned)f2bf(aB1) << 16);
        }
      }
    }
  };

  if (cnt <= ECAP) {
    proc([&](int i) { return erec[i]; });
  } else {
    proc([&](int i) { return epack[base + i]; });  // fallback (≈never)
  }
}

// ---------------- host launcher ----------------
extern "C" void kernel_launch(void* const* d_in, const int* in_sizes, int n_in,
                              void* d_out, int out_size, void* d_ws, size_t ws_size,
                              hipStream_t stream) {
  const float* x  = (const float*)d_in[0];
  const float* W1 = (const float*)d_in[1];
  const float* b1 = (const float*)d_in[2];
  const float* W2 = (const float*)d_in[3];
  const float* b2 = (const float*)d_in[4];
  const int*   eb = (const int*)d_in[5];
  float* out = (float*)d_out;

  char* ws = (char*)d_ws;
  size_t off = 0;
  auto alloc = [&](size_t bytes) -> void* {
    void* p = ws + off;
    off = (off + bytes + 255) & ~(size_t)255;
    return p;
  };

  int*   flagp  = (int*)alloc(256);
  int*   cnt    = (int*)alloc(N_NODES * sizeof(int));
  int*   ptr    = (int*)alloc((N_NODES + 1) * sizeof(int));
  int*   cursor = (int*)alloc(N_NODES * sizeof(int));
  int*   bsum   = (int*)alloc(256 * sizeof(int));
  float* dinv   = (float*)alloc(N_NODES * sizeof(float));
  float* selfw  = (float*)alloc(N_NODES * sizeof(float));
  int2*  epack  = (int2*)alloc((size_t)N_EDGES * sizeof(int2));
  unsigned short* W1T = (unsigned short*)alloc((size_t)HID * F_INDIM * sizeof(unsigned short));
  unsigned short* W2T = (unsigned short*)alloc((size_t)N_CLS * HID * sizeof(unsigned short));
  unsigned int* x0h = (unsigned int*)alloc((size_t)N_NODES * 32 * sizeof(unsigned int));
  unsigned int* z1  = (unsigned int*)alloc((size_t)N_NODES * 32 * sizeof(unsigned int));
  unsigned int* z2  = (unsigned int*)alloc((size_t)N_NODES * 32 * sizeof(unsigned int));

  int nchunks = 1;
  while (nchunks < 16) {
    size_t hbytes = (size_t)(N_NODES / nchunks) * HID * sizeof(unsigned short);
    if (off + hbytes <= ws_size) break;
    nchunks <<= 1;
  }
  int Mc = N_NODES / nchunks;
  unsigned short* h = (unsigned short*)alloc((size_t)Mc * HID * sizeof(unsigned short));

  hipMemsetAsync(cnt, 0, N_NODES * sizeof(int), stream);
  detect_kernel<<<1, 256, 0, stream>>>(eb, flagp);
  count_kernel<<<(N_EDGES + 255) / 256, 256, 0, stream>>>(eb, flagp, cnt);
  int nblk = (N_NODES + 255) / 256;
  scan1_kernel<<<nblk, 256, 0, stream>>>(cnt, ptr, bsum);
  scan2_kernel<<<1, 256, 0, stream>>>(bsum, nblk);
  scan3_kernel<<<nblk, 256, 0, stream>>>(ptr, bsum);
  dinv_kernel<<<nblk, 256, 0, stream>>>(cnt, ptr, dinv, selfw, cursor);
  fill_kernel<<<(N_EDGES + 255) / 256, 256, 0, stream>>>(eb, flagp, dinv, cursor, epack);
  prep_w<<<(F_INDIM * HID + HID * N_CLS + 255) / 256, 256, 0, stream>>>(W1, W2, W1T, W2T);

  for (int ci = 0; ci < nchunks; ++ci) {
    const float* Achunk = x + (size_t)ci * Mc * F_INDIM;
    dim3 g1((Mc + 63) / 64, HID / 128);
    gemm1_mfma<<<g1, 256, 0, stream>>>(Achunk, W1T, b1, h, Mc);
    dim3 g2((Mc + 63) / 64, 1);
    gemm2_mfma<<<g2, 256, 0, stream>>>(h, W2T, b2,
        (unsigned short*)x0h, ci * Mc, Mc);
  }

  int pgrid = (N_NODES + NPB - 1) / NPB;  // 1563
  const unsigned int* zin = x0h;
  unsigned int* zo[2] = {z1, z2};
  for (int s = 0; s < K_STEPS - 1; ++s) {
    unsigned int* zout = zo[s & 1];
    prop_step<false><<<pgrid, 256, 0, stream>>>(zin, x0h, selfw, ptr, epack, zout, nullptr);
    zin = zout;
  }
  prop_step<true><<<pgrid, 256, 0, stream>>>(zin, x0h, selfw, ptr, epack, nullptr, out);
}

// Round 8
// 379.925 us; speedup vs baseline: 1.6116x; 1.1686x over previous
//
#include <hip/hip_runtime.h>

#define N_NODES 50000
#define N_EDGES 800000
#define F_INDIM 512
#define HID     256
#define N_CLS   64
#define K_STEPS 10
#define ALPHA_V 0.1f

#define NPB 28     // nodes per prop block (4 waves x 7)
#define NPW 7
#define ECAP 1536  // LDS edge-record capacity (mean 448, 12 KB)

typedef __attribute__((ext_vector_type(8))) short short8;
typedef __attribute__((ext_vector_type(4))) float f32x4;
typedef __attribute__((ext_vector_type(4))) unsigned short ushort4v;

__device__ __forceinline__ unsigned short f2bf(float f) {
  unsigned u = __builtin_bit_cast(unsigned, f);
  unsigned r = (u + 0x7fffu + ((u >> 16) & 1u)) >> 16;
  return (unsigned short)r;
}
__device__ __forceinline__ float bflo(unsigned g) {
  return __builtin_bit_cast(float, g << 16);
}
__device__ __forceinline__ float bfhi(unsigned g) {
  return __builtin_bit_cast(float, g & 0xffff0000u);
}

#define GLOAD_LDS16(g, l)                                                        \
  __builtin_amdgcn_global_load_lds(                                              \
      (const __attribute__((address_space(1))) unsigned int*)(g),                \
      (__attribute__((address_space(3))) unsigned int*)(l), 16, 0, 0)

// ---------------- edge dtype detection ----------------
__global__ void detect_kernel(const int* __restrict__ eb, int* __restrict__ flag) {
  __shared__ int any;
  if (threadIdx.x == 0) any = 0;
  __syncthreads();
  for (int j = threadIdx.x; j < 1024; j += 256) {
    if (eb[2 * j + 1] != 0) atomicOr(&any, 1);
  }
  __syncthreads();
  if (threadIdx.x == 0) flag[0] = any ? 0 : 1;  // 1 => int64 stride, 0 => int32
}

// ---------------- degree histogram over targets ----------------
__global__ void count_kernel(const int* __restrict__ eb, const int* __restrict__ flagp,
                             int* __restrict__ cnt) {
  int e = blockIdx.x * 256 + threadIdx.x;
  if (e >= N_EDGES) return;
  int sh = flagp[0];
  int c = eb[((size_t)(N_EDGES + e)) << sh];
  atomicAdd(&cnt[c], 1);
}

// ---------------- 3-kernel exclusive scan ----------------
__global__ void scan1_kernel(const int* __restrict__ cnt, int* __restrict__ ptr,
                             int* __restrict__ bsum) {
  __shared__ int sm[256];
  int t = threadIdx.x;
  int i = blockIdx.x * 256 + t;
  int v = (i < N_NODES) ? cnt[i] : 0;
  sm[t] = v;
  __syncthreads();
  for (int off = 1; off < 256; off <<= 1) {
    int x = sm[t];
    if (t >= off) x += sm[t - off];
    __syncthreads();
    sm[t] = x;
    __syncthreads();
  }
  int incl = sm[t];
  if (i < N_NODES) ptr[i] = incl - v;
  if (t == 255) bsum[blockIdx.x] = incl;
}

__global__ void scan2_kernel(int* __restrict__ bsum, int nblk) {
  __shared__ int sm[256];
  int t = threadIdx.x;
  int v = (t < nblk) ? bsum[t] : 0;
  sm[t] = v;
  __syncthreads();
  for (int off = 1; off < 256; off <<= 1) {
    int x = sm[t];
    if (t >= off) x += sm[t - off];
    __syncthreads();
    sm[t] = x;
    __syncthreads();
  }
  int incl = sm[t];
  if (t < nblk) bsum[t] = incl - v;
}

__global__ void scan3_kernel(int* __restrict__ ptr, const int* __restrict__ bsum) {
  int i = blockIdx.x * 256 + threadIdx.x;
  if (i < N_NODES) ptr[i] += bsum[i >> 8];
  if (i == 0) ptr[N_NODES] = N_EDGES;
}

// ---------------- dinv + selfw + cursor init ----------------
__global__ void dinv_kernel(const int* __restrict__ cnt, const int* __restrict__ ptr,
                            float* __restrict__ dinv, float* __restrict__ selfw,
                            int* __restrict__ cursor) {
  int i = blockIdx.x * 256 + threadIdx.x;
  if (i >= N_NODES) return;
  float di = rsqrtf((float)cnt[i] + 1.0f);
  dinv[i] = di;
  selfw[i] = (1.0f - ALPHA_V) * di * di;
  cursor[i] = ptr[i];
}

// ---------------- CSR fill (by target), packed (src, weight) ----------------
__global__ void fill_kernel(const int* __restrict__ eb, const int* __restrict__ flagp,
                            const float* __restrict__ dinv, int* __restrict__ cursor,
                            int2* __restrict__ epack) {
  int e = blockIdx.x * 256 + threadIdx.x;
  if (e >= N_EDGES) return;
  int sh = flagp[0];
  int r = eb[((size_t)e) << sh];
  int c = eb[((size_t)(N_EDGES + e)) << sh];
  int pos = atomicAdd(&cursor[c], 1);
  float w = (1.0f - ALPHA_V) * dinv[r] * dinv[c];
  epack[pos] = make_int2(r, __float_as_int(w));
}

// ---------------- weight transpose + bf16 prepass ----------------
__global__ void prep_w(const float* __restrict__ W1, const float* __restrict__ W2,
                       unsigned short* __restrict__ W1T, unsigned short* __restrict__ W2T) {
  int i = blockIdx.x * 256 + threadIdx.x;
  if (i < F_INDIM * HID) {
    int k = i >> 8, c = i & 255;
    W1T[(size_t)c * F_INDIM + k] = f2bf(W1[i]);
  }
  int j = i - F_INDIM * HID;
  if (j >= 0 && j < HID * N_CLS) {
    int k = j >> 6, c = j & 63;
    W2T[(size_t)c * HID + k] = f2bf(W2[j]);
  }
}

// ---------------- GEMM1: tile 128x128x32, 4 waves (2x2), LDS dbuf ------------
// A fp32 loaded as contiguous chunks -> in-reg cvt -> swizzled ds_write.
// B via global_load_lds with pre-swizzled source. 16 MFMA per phase per wave.
__global__ __launch_bounds__(256, 4) void gemm1_mfma(
    const float* __restrict__ A, const unsigned short* __restrict__ BT,
    const float* __restrict__ bias, unsigned short* __restrict__ H, int M) {
  __shared__ unsigned short Ab[2][128 * 32];   // 8 KB each
  __shared__ unsigned short Bb[2][128 * 32];   // 8 KB each
  const int t = threadIdx.x;
  const int wave = t >> 6, lane = t & 63;
  const int wr = wave >> 1, wc = wave & 1;
  const int l15 = lane & 15, l4 = lane >> 4;
  const int row0 = blockIdx.x * 128, col0 = blockIdx.y * 128;

  f32x4 acc[4][4];
#pragma unroll
  for (int m = 0; m < 4; ++m)
#pragma unroll
    for (int n = 0; n < 4; ++n) acc[m][n] = (f32x4)0.0f;

  const int NT = F_INDIM / 32;  // 16

  auto stageB = [&](int buf, int kt) {
#pragma unroll
    for (int i = 0; i < 2; ++i) {
      int row = wave * 32 + i * 16 + (lane >> 2);
      int g = lane & 3;
      int kg = g ^ ((row >> 1) & 3);
      const unsigned short* src = BT + (size_t)(col0 + row) * F_INDIM + kt * 32 + kg * 8;
      unsigned short* dst = &Bb[buf][(wave * 32 + i * 16) * 32];
      GLOAD_LDS16(src, dst);
    }
  };
  f32x4 ar[4];
  int arow[4], acol[4];
  auto loadA = [&](int kt) {
#pragma unroll
    for (int i = 0; i < 4; ++i) {
      int idx = (i * 256 + t) * 4;   // flat float idx in 128x32 tile
      int row = idx >> 5;
      int col = idx & 31;
      arow[i] = row; acol[i] = col;
      int gr = row0 + row;
      if (gr > M - 1) gr = M - 1;
      ar[i] = *(const f32x4*)(A + (size_t)gr * F_INDIM + kt * 32 + col);
    }
  };
  auto writeA = [&](int buf) {
#pragma unroll
    for (int i = 0; i < 4; ++i) {
      int row = arow[i], col = acol[i];
      int g = col >> 3;
      int gp = g ^ ((row >> 1) & 3);
      ushort4v o;
#pragma unroll
      for (int j = 0; j < 4; ++j) o[j] = f2bf(ar[i][j]);
      *(ushort4v*)(&Ab[buf][row * 32 + gp * 8 + (col & 7)]) = o;
    }
  };
  auto compute = [&](int buf) {
    short8 af[4], bf[4];
#pragma unroll
    for (int m = 0; m < 4; ++m) {
      int rowA = wr * 64 + m * 16 + l15;
      af[m] = *(const short8*)(&Ab[buf][rowA * 32 + (l4 ^ ((rowA >> 1) & 3)) * 8]);
    }
#pragma unroll
    for (int n = 0; n < 4; ++n) {
      int c = wc * 64 + n * 16 + l15;
      bf[n] = *(const short8*)(&Bb[buf][c * 32 + (l4 ^ ((c >> 1) & 3)) * 8]);
    }
#pragma unroll
    for (int m = 0; m < 4; ++m)
#pragma unroll
      for (int n = 0; n < 4; ++n)
        acc[m][n] = __builtin_amdgcn_mfma_f32_16x16x32_bf16(af[m], bf[n], acc[m][n], 0, 0, 0);
  };

  stageB(0, 0);
  loadA(0);
  writeA(0);
  __syncthreads();
#pragma unroll 4
  for (int kt = 0; kt < NT; ++kt) {
    int cur = kt & 1;
    if (kt + 1 < NT) {
      stageB(cur ^ 1, kt + 1);
      loadA(kt + 1);
    }
    compute(cur);
    if (kt + 1 < NT) writeA(cur ^ 1);
    __syncthreads();
  }

  float bv[4];
#pragma unroll
  for (int n = 0; n < 4; ++n) bv[n] = bias[col0 + wc * 64 + n * 16 + l15];
#pragma unroll
  for (int m = 0; m < 4; ++m)
#pragma unroll
    for (int i = 0; i < 4; ++i) {
      int grow = row0 + wr * 64 + m * 16 + l4 * 4 + i;
      if (grow >= M) continue;
#pragma unroll
      for (int n = 0; n < 4; ++n) {
        int gcol = col0 + wc * 64 + n * 16 + l15;
        float v = fmaxf(acc[m][n][i] + bv[n], 0.0f);
        H[(size_t)grow * HID + gcol] = f2bf(v);
      }
    }
}

// ---------------- GEMM2: x0 = h @ W2 + b2 -> bf16 flat [N][64] ----------------
__global__ __launch_bounds__(256) void gemm2_mfma(
    const unsigned short* __restrict__ Hm, const unsigned short* __restrict__ BT,
    const float* __restrict__ bias, unsigned short* __restrict__ Ch,
    int roff, int M) {
  const int t = threadIdx.x;
  const int wave = t >> 6, lane = t & 63;
  const int l15 = lane & 15, l4 = lane >> 4;
  const int row0 = blockIdx.x * 64 + wave * 16;

  f32x4 acc[4];
#pragma unroll
  for (int n = 0; n < 4; ++n) acc[n] = (f32x4)0.0f;

  int gr = row0 + l15;
  if (gr > M - 1) gr = M - 1;
  const unsigned short* arow = Hm + (size_t)gr * HID + l4 * 8;

#pragma unroll
  for (int kt = 0; kt < HID / 32; ++kt) {
    short8 af = *(const short8*)(arow + kt * 32);
    short8 bf[4];
#pragma unroll
    for (int n = 0; n < 4; ++n)
      bf[n] = *(const short8*)(BT + (size_t)(n * 16 + l15) * HID + kt * 32 + l4 * 8);
#pragma unroll
    for (int n = 0; n < 4; ++n)
      acc[n] = __builtin_amdgcn_mfma_f32_16x16x32_bf16(af, bf[n], acc[n], 0, 0, 0);
  }

#pragma unroll
  for (int n = 0; n < 4; ++n) {
    int gcol = n * 16 + l15;
    float bv = bias[gcol];
#pragma unroll
    for (int i = 0; i < 4; ++i) {
      int grow = row0 + l4 * 4 + i;
      if (grow < M) {
        float v = acc[n][i] + bv;
        Ch[(size_t)(roff + grow) * N_CLS + gcol] = f2bf(v);
      }
    }
  }
}

// ---------------- propagation (round-6 form): LDS-cached CSR slice ------------
template <bool LAST>
__global__ __launch_bounds__(256) void prop_step(
    const unsigned int* __restrict__ zin, const unsigned int* __restrict__ x0h,
    const float* __restrict__ selfw, const int* __restrict__ ptr,
    const int2* __restrict__ epack, unsigned int* __restrict__ zout,
    float* __restrict__ outf) {
  __shared__ int2 erec[ECAP];
  __shared__ int lptr[NPB + 1];
  __shared__ float lsw[NPB];

  const int tid = threadIdx.x;
  const int n0 = blockIdx.x * NPB;
  int nEnd = N_NODES - n0;
  if (nEnd > NPB) nEnd = NPB;

  if (tid <= nEnd) lptr[tid] = ptr[n0 + tid];
  if (tid < nEnd) lsw[tid] = selfw[n0 + tid];
  __syncthreads();
  const int base = lptr[0];
  const int cnt = lptr[nEnd] - base;
  for (int i = tid; i < cnt && i < ECAP; i += 256) erec[i] = epack[base + i];
  __syncthreads();

  const int wv = tid >> 6, lane = tid & 63;
  const int half = lane >> 5, cl = lane & 31;

  auto run = [&](auto getrec) {
    for (int ni = wv * NPW; ni < wv * NPW + NPW; ++ni) {
      if (ni >= nEnd) break;
      const int node = n0 + ni;
      float a0 = 0.0f, a1 = 0.0f;
      if (half == 0) {
        unsigned zs = zin[(size_t)node * 32 + cl];
        unsigned xs = x0h[(size_t)node * 32 + cl];
        float sw = lsw[ni];
        a0 = fmaf(sw, bflo(zs), ALPHA_V * bflo(xs));
        a1 = fmaf(sw, bfhi(zs), ALPHA_V * bfhi(xs));
      }
      int e = lptr[ni] - base, e1 = lptr[ni + 1] - base;
      for (; e + 16 <= e1; e += 16) {
        int2 p[8];
#pragma unroll
        for (int j = 0; j < 8; ++j) p[j] = getrec(e + 2 * j + half);
        unsigned g[8];
#pragma unroll
        for (int j = 0; j < 8; ++j) g[j] = zin[(size_t)p[j].x * 32 + cl];
#pragma unroll
        for (int j = 0; j < 8; ++j) {
          float w = __int_as_float(p[j].y);
          a0 = fmaf(w, bflo(g[j]), a0);
          a1 = fmaf(w, bfhi(g[j]), a1);
        }
      }
      if (e < e1) {
        int2 p[8];
        float m[8];
#pragma unroll
        for (int j = 0; j < 8; ++j) {
          int gi = e + 2 * j + half;
          bool ok = gi < e1;
          p[j] = getrec(ok ? gi : e);
          m[j] = ok ? 1.0f : 0.0f;
        }
        unsigned g[8];
#pragma unroll
        for (int j = 0; j < 8; ++j) g[j] = zin[(size_t)p[j].x * 32 + cl];
#pragma unroll
        for (int j = 0; j < 8; ++j) {
          float w = m[j] * __int_as_float(p[j].y);
          a0 = fmaf(w, bflo(g[j]), a0);
          a1 = fmaf(w, bfhi(g[j]), a1);
        }
      }
      a0 += __shfl_xor(a0, 32);
      a1 += __shfl_xor(a1, 32);
      if (half == 0) {
        if (LAST) {
          *(float2*)(outf + (size_t)node * 64 + 2 * cl) = make_float2(a0, a1);
        } else {
          zout[(size_t)node * 32 + cl] =
              (unsigned)f2bf(a0) | ((unsigned)f2bf(a1) << 16);
        }
      }
    }
  };

  if (cnt <= ECAP) {
    run([&](int i) { return erec[i]; });
  } else {
    run([&](int i) { return epack[base + i]; });  // fallback (≈never)
  }
}

// ---------------- host launcher ----------------
extern "C" void kernel_launch(void* const* d_in, const int* in_sizes, int n_in,
                              void* d_out, int out_size, void* d_ws, size_t ws_size,
                              hipStream_t stream) {
  const float* x  = (const float*)d_in[0];
  const float* W1 = (const float*)d_in[1];
  const float* b1 = (const float*)d_in[2];
  const float* W2 = (const float*)d_in[3];
  const float* b2 = (const float*)d_in[4];
  const int*   eb = (const int*)d_in[5];
  float* out = (float*)d_out;

  char* ws = (char*)d_ws;
  size_t off = 0;
  auto alloc = [&](size_t bytes) -> void* {
    void* p = ws + off;
    off = (off + bytes + 255) & ~(size_t)255;
    return p;
  };

  int*   flagp  = (int*)alloc(256);
  int*   cnt    = (int*)alloc(N_NODES * sizeof(int));
  int*   ptr    = (int*)alloc((N_NODES + 1) * sizeof(int));
  int*   cursor = (int*)alloc(N_NODES * sizeof(int));
  int*   bsum   = (int*)alloc(256 * sizeof(int));
  float* dinv   = (float*)alloc(N_NODES * sizeof(float));
  float* selfw  = (float*)alloc(N_NODES * sizeof(float));
  int2*  epack  = (int2*)alloc((size_t)N_EDGES * sizeof(int2));
  unsigned short* W1T = (unsigned short*)alloc((size_t)HID * F_INDIM * sizeof(unsigned short));
  unsigned short* W2T = (unsigned short*)alloc((size_t)N_CLS * HID * sizeof(unsigned short));
  unsigned int* x0h = (unsigned int*)alloc((size_t)N_NODES * 32 * sizeof(unsigned int));
  unsigned int* z1  = (unsigned int*)alloc((size_t)N_NODES * 32 * sizeof(unsigned int));
  unsigned int* z2  = (unsigned int*)alloc((size_t)N_NODES * 32 * sizeof(unsigned int));

  int nchunks = 1;
  while (nchunks < 16) {
    size_t hbytes = (size_t)(N_NODES / nchunks) * HID * sizeof(unsigned short);
    if (off + hbytes <= ws_size) break;
    nchunks <<= 1;
  }
  int Mc = N_NODES / nchunks;
  unsigned short* h = (unsigned short*)alloc((size_t)Mc * HID * sizeof(unsigned short));

  hipMemsetAsync(cnt, 0, N_NODES * sizeof(int), stream);
  detect_kernel<<<1, 256, 0, stream>>>(eb, flagp);
  count_kernel<<<(N_EDGES + 255) / 256, 256, 0, stream>>>(eb, flagp, cnt);
  int nblk = (N_NODES + 255) / 256;
  scan1_kernel<<<nblk, 256, 0, stream>>>(cnt, ptr, bsum);
  scan2_kernel<<<1, 256, 0, stream>>>(bsum, nblk);
  scan3_kernel<<<nblk, 256, 0, stream>>>(ptr, bsum);
  dinv_kernel<<<nblk, 256, 0, stream>>>(cnt, ptr, dinv, selfw, cursor);
  fill_kernel<<<(N_EDGES + 255) / 256, 256, 0, stream>>>(eb, flagp, dinv, cursor, epack);
  prep_w<<<(F_INDIM * HID + HID * N_CLS + 255) / 256, 256, 0, stream>>>(W1, W2, W1T, W2T);

  for (int ci = 0; ci < nchunks; ++ci) {
    const float* Achunk = x + (size_t)ci * Mc * F_INDIM;
    dim3 g1((Mc + 127) / 128, HID / 128);
    gemm1_mfma<<<g1, 256, 0, stream>>>(Achunk, W1T, b1, h, Mc);
    dim3 g2((Mc + 63) / 64, 1);
    gemm2_mfma<<<g2, 256, 0, stream>>>(h, W2T, b2,
        (unsigned short*)x0h, ci * Mc, Mc);
  }

  int pgrid = (N_NODES + NPB - 1) / NPB;  // 1786
  const unsigned int* zin = x0h;
  unsigned int* zo[2] = {z1, z2};
  for (int s = 0; s < K_STEPS - 1; ++s) {
    unsigned int* zout = zo[s & 1];
    prop_step<false><<<pgrid, 256, 0, stream>>>(zin, x0h, selfw, ptr, epack, zout, nullptr);
    zin = zout;
  }
  prop_step<true><<<pgrid, 256, 0, stream>>>(zin, x0h, selfw, ptr, epack, nullptr, out);
}